// Round 9
// baseline (106.169 us; speedup 1.0000x reference)
//
#include <hip/hip_runtime.h>
#include <math.h>
#include <utility>

#define BB 64
#define NN 512
#define DD 32
#define ZD 34            // DD + 2 (x..., t, y)
#define NE 595           // ZD*(ZD+1)/2 upper-triangular entries
#define WIN 8
#define NW 64            // NN / WIN windows
#define WACT 60          // active windows w = 4..63 (n <= 31 is rank-deficient -> 0)

// fused gram+scan geometry (entry-per-thread, 128-row segments)
#define SEG 4            // s-segments per batch (128 rows each)
#define RS 128           // rows per segment
#define KWS 16           // windows per segment
#define CH 4             // e-chunks per (b,seg)
#define ECH 149          // entries per chunk (4*149 >= 595)
#define PSTRIDE 17       // 16 exclusive in-segment snapshots + segment total

using f2 = __attribute__((ext_vector_type(2))) float;

// entry e -> (i,j), i <= j, row-major upper triangle of ZD x ZD
__device__ inline void ent2ij(int e, int& i, int& j) {
    int ii = 0, rem = e;
    while (rem >= ZD - ii) { rem -= (ZD - ii); ++ii; }
    i = ii; j = ii + rem;
}

// ---- recursive struct-of-scalars: SROA-guaranteed register residency ----
template<int N> struct Pack { Pack<N - 1> head; float v; };
template<> struct Pack<1> { float v; };
template<int I, int N> __device__ __forceinline__ float& pget(Pack<N>& p) {
    static_assert(I < N, "oob");
    if constexpr (I == N - 1) return p.v;
    else return pget<I, N - 1>(p.head);
}

// float2-pair variant (pair p = rows 2p, 2p+1)
template<int N> struct PackP { PackP<N - 1> head; f2 v; };
template<> struct PackP<1> { f2 v; };
template<int I, int N> __device__ __forceinline__ f2& ppget(PackP<N>& p) {
    static_assert(I < N, "oob");
    if constexpr (I == N - 1) return p.v;
    else return ppget<I, N - 1>(p.head);
}
template<int R> __device__ __forceinline__ float prow(PackP<21>& p) {
    static_assert(R < 42, "oob");
    if constexpr (R & 1) return ppget<R / 2>(p).y;
    else                 return ppget<R / 2>(p).x;
}

__device__ __forceinline__ float rdlane(float x, int srclane) {
    return __int_as_float(__builtin_amdgcn_readlane(__float_as_int(x), srclane));
}
__device__ __forceinline__ float bperm(int byteaddr, float x) {
    return __int_as_float(__builtin_amdgcn_ds_bpermute(byteaddr, __float_as_int(x)));
}

// Fused window-partial + prefix-scan. Block = (b, s-segment, e-chunk).
// Each thread owns ONE triangle entry e. ILP form: 16 INDEPENDENT 8-fma fp64
// window partials + 16 serial adds. Emits 16 exclusive window snapshots +
// segment total to P[b][seg][17][NE]. Folds output init: logs[.]=0, means=0
// for n < 32.
__global__ __launch_bounds__(256) void dml_gram(const float* __restrict__ xtys,
                                                float* __restrict__ P,
                                                float* __restrict__ out) {
    const int t   = threadIdx.x;
    const int blk = blockIdx.x;                  // ((b*SEG + g)*CH + c)
    const int c   = blk % CH;
    const int bg  = blk / CH;
    const int g   = bg % SEG;
    const int b   = bg / SEG;

    const int gid = blk * 256 + t;
    if (gid < BB * NN) out[BB * NN + gid] = 0.0f;
    if (gid < BB * DD) out[(gid >> 5) * NN + (gid & 31)] = 0.0f;

    __shared__ float zs[RS * ZD];                // 17408 B
    const float* src = xtys + ((size_t)b * NN + (size_t)g * RS) * ZD;
    for (int u = t; u < RS * ZD; u += 256) zs[u] = src[u];
    __syncthreads();

    const int e = c * ECH + t;
    if (t < ECH && e < NE) {
        int i, j;
        ent2ij(e, i, j);
        float* pdst = P + (size_t)(b * SEG + g) * PSTRIDE * NE + e;
        double acc = 0.0;
#pragma unroll
        for (int k = 0; k < KWS; ++k) {
            pdst[k * NE] = (float)acc;           // exclusive: before window k's rows
            double wsum = 0.0;                   // independent chain per window
#pragma unroll
            for (int s8 = 0; s8 < WIN; ++s8) {
                const float* row = &zs[(k * WIN + s8) * ZD];
                wsum = fma((double)row[i], (double)row[j], wsum);
            }
            acc += wsum;
        }
        pdst[KWS * NE] = (float)acc;             // segment total
    }
}

// ---- solve: lane = COLUMN j of the symmetric bordered 42x42 matrix
// [[G0, W],[W^T, 0]], W = [x_1..x_8, Xtt0, Xty0]; A[r] = M[r][j] as 21 f2
// pairs. TWO INDEPENDENT SYSTEMS PER WAVE, fully interleaved: every
// rdlane->rcp->fma chain of system a is hidden by the twin chain of system b
// (ILP-2 software pipeline; measured VALUBusy ~45% => >50% stall headroom).
// Pair (K>>1) at even K touches dead pivot row K — safe: pivot rows are only
// read (piv, t) BEFORE their own step's updates, never afterwards.

template<int R> __device__ __forceinline__
float initval(int j, int off_j, int zoff, const float* snL, const float* zb) {
    constexpr int RC = (R < DD) ? (R * ZD - (R * (R - 1)) / 2 - R) : 0;
    if constexpr (R < DD) {
        float v = 0.0f;
        if (j < DD) {
            int idx = (R < j) ? (RC + j) : (off_j + R);
            v = snL[idx];
        } else if (j < DD + WIN) {
            v = zb[zoff + R];
        } else if (j == 40) {
            v = snL[RC + DD];                    // Xtt0[R]
        } else if (j == 41) {
            v = snL[RC + DD + 1];                // Xty0[R]
        }
        return v;
    } else if constexpr (R < DD + WIN) {
        return (j < DD) ? zb[(R - DD) * ZD + j] : 0.0f;
    } else if constexpr (R == 40) {
        return (j < DD) ? snL[off_j + DD] : 0.0f;
    } else {
        return (j < DD) ? snL[off_j + DD + 1] : 0.0f;
    }
}
template<int P> __device__ __forceinline__
void init_rec(PackP<21>& A, int j, int off_j, int zoff,
              const float* snL, const float* zb) {
    if constexpr (P < 21) {
        f2 q;
        q.x = initval<2 * P>(j, off_j, zoff, snL, zb);
        q.y = initval<2 * P + 1>(j, off_j, zoff, snL, zb);
        ppget<P>(A) = q;
        init_rec<P + 1>(A, j, off_j, zoff, snL, zb);
    }
}

template<int K, int P> __device__ __forceinline__
void elim_pairs2(PackP<21>& Aa, PackP<21>& Ab, f2 ta, f2 tb) {
    if constexpr (P < 21) {
        f2 fa, fb;
        fa.x = rdlane(prow<2 * P>(Aa), K);       // M[2P][K], wave-uniform
        fa.y = rdlane(prow<2 * P + 1>(Aa), K);
        fb.x = rdlane(prow<2 * P>(Ab), K);
        fb.y = rdlane(prow<2 * P + 1>(Ab), K);
        ppget<P>(Aa) -= fa * ta;
        ppget<P>(Ab) -= fb * tb;
        elim_pairs2<K, P + 1>(Aa, Ab, ta, tb);
    }
}
template<int K> __device__ __forceinline__
void elim_step2(PackP<21>& Aa, PackP<21>& Ab) {
    float pa = rdlane(prow<K>(Aa), K);           // M[K][K] of each system
    float pb = rdlane(prow<K>(Ab), K);
    float ia = (pa > 1e-30f) ? 1.0f / pa : 0.0f;
    float ib = (pb > 1e-30f) ? 1.0f / pb : 0.0f;
    float ua = ia * prow<K>(Aa);                 // t_j; 0 for done cols
    float ub = ib * prow<K>(Ab);
    f2 ta; ta.x = ua; ta.y = ua;
    f2 tb; tb.x = ub; tb.y = ub;
    elim_pairs2<K, (K + 1) / 2>(Aa, Ab, ta, tb);
}
template<int... Ks> __device__ __forceinline__
void elim_all2(PackP<21>& Aa, PackP<21>& Ab, std::integer_sequence<int, Ks...>) {
    ((elim_step2<Ks>(Aa, Ab)), ...);
}

template<int R> __device__ __forceinline__
void kdump(PackP<21>& A, float* Kl, int c) {     // lanes 32..41: column c of K
    if constexpr (R < DD + 10) {
        if constexpr (R >= DD)
            Kl[(R - DD) * 10 + c] = -prow<R>(A);
        kdump<R + 1>(A, Kl, c);
    }
}

// ---- row-parallel 8x8 GJ, dual-interleaved: lane = (sys, row). Each lane
// holds ONE row (12 floats) per system; pivot-row broadcast via ds_bpermute
// within the 8-lane group. Inactive rows (row > sys) are identity rows with
// zero RHS -> f = 0 forever, contribute exactly 0.
template<int L> __device__ __forceinline__
void tinit(Pack<12>& T, int row, int sys, const float* Kl, const float* zb) {
    if constexpr (L < 12) {
        float v;
        if constexpr (L < 8) {
            float kij = (row <= sys && L <= sys) ? Kl[row * 10 + L] : 0.0f;
            v = kij + ((row == L) ? 1.0f : 0.0f);
        } else if constexpr (L == 8)  v = (row <= sys) ? Kl[row * 10 + 8] : 0.0f;       // KUp
        else if constexpr (L == 9)    v = (row <= sys) ? zb[row * ZD + DD] : 0.0f;      // t_i
        else if constexpr (L == 10)   v = (row <= sys) ? Kl[row * 10 + 9] : 0.0f;       // KUq
        else                          v = (row <= sys) ? zb[row * ZD + DD + 1] : 0.0f;  // y_i
        pget<L>(T) = v;
        tinit<L + 1>(T, row, sys, Kl, zb);
    }
}
template<int K, int J> __device__ __forceinline__
void gjp_cols2(Pack<12>& Ta, Pack<12>& Tb, float fa, float fb, int pb) {
    if constexpr (J < 12) {
        float pka = bperm(pb + 4 * K, pget<J>(Ta));   // pivot row K, col J
        float pkb = bperm(pb + 4 * K, pget<J>(Tb));
        pget<J>(Ta) = fmaf(-fa, pka, pget<J>(Ta));
        pget<J>(Tb) = fmaf(-fb, pkb, pget<J>(Tb));
        gjp_cols2<K, J + 1>(Ta, Tb, fa, fb, pb);
    }
}
template<int K> __device__ __forceinline__
void gjp_step2(Pack<12>& Ta, Pack<12>& Tb, int pb, int row,
               float& diag_a, float& diag_b) {
    float pka  = bperm(pb + 4 * K, pget<K>(Ta));      // M[K][K] of own system
    float pkb  = bperm(pb + 4 * K, pget<K>(Tb));
    float ia   = (pka > 1e-30f || pka < -1e-30f) ? 1.0f / pka : 0.0f;
    float ib   = (pkb > 1e-30f || pkb < -1e-30f) ? 1.0f / pkb : 0.0f;
    float fa   = (row == K) ? 0.0f : pget<K>(Ta) * ia;
    float fb   = (row == K) ? 0.0f : pget<K>(Tb) * ib;
    gjp_cols2<K, K + 1>(Ta, Tb, fa, fb, pb);
    if (row == K) { diag_a = pget<K>(Ta); diag_b = pget<K>(Tb); }
}
template<int... Ks> __device__ __forceinline__
void gjp_all2(Pack<12>& Ta, Pack<12>& Tb, int pb, int row,
              float& diag_a, float& diag_b, std::integer_sequence<int, Ks...>) {
    ((gjp_step2<Ks>(Ta, Tb, pb, row, diag_a, diag_b)), ...);
}

// ONE WAVE per WG, TWO systems per wave (ids 2*blk, 2*blk+1 — adjacent, so
// they share the batch's P segments -> L2 locality). 1920 WGs = 7.5/CU
// (128 CUs x 8, 128 x 7 — near-perfect balance; ~8 one-wave WGs/CU proven
// resident in round 2). Private per-wave LDS, no barriers (DS in-order).
// Snapshot Sn[w] = piece[g][k] + sum_{g'<g} total[g'], g=w>>4, k=w&15.
//   den = Stt0 - Kpp + sum_i (KpU_i - t_i)(s1_i - s2_i), s1=S^-1 KUp, s2=S^-1 t
//   num = Sty0 - Kpq + sum_i (KpU_i - t_i)(r1_i - r2_i), r1=S^-1 KUq, r2=S^-1 y
__global__ __launch_bounds__(64) void dml_solve(const float* __restrict__ xtys,
                                                const float* __restrict__ P,
                                                float* __restrict__ out) {
    const int lane = threadIdx.x;
    const int ida  = blockIdx.x * 2;
    const int idb  = ida + 1;
    const int wa   = (ida % WACT) + 4;
    const int ba   = ida / WACT;
    const int wb   = (idb % WACT) + 4;
    const int bb   = idb / WACT;
    const int ga   = wa >> 4, ka = wa & 15;
    const int gb   = wb >> 4, kb = wb & 15;

    __shared__ float snL[2][NE];
    __shared__ float zbS[2][WIN * ZD];
    __shared__ float KlS[2][100];        // K = W^T G0^-1 W (10x10)

    const float* pba  = P + (size_t)ba * SEG * PSTRIDE * NE;
    const float* pbb  = P + (size_t)bb * SEG * PSTRIDE * NE;
    const float* sra  = xtys + ((size_t)ba * NN + (size_t)wa * WIN) * ZD;
    const float* srb  = xtys + ((size_t)bb * NN + (size_t)wb * WIN) * ZD;
    for (int u = lane; u < NE; u += 64) {
        float va = pba[(size_t)(ga * PSTRIDE + ka) * NE + u];
        float vb = pbb[(size_t)(gb * PSTRIDE + kb) * NE + u];
        for (int g2 = 0; g2 < ga; ++g2)
            va += pba[(size_t)(g2 * PSTRIDE + KWS) * NE + u];
        for (int g2 = 0; g2 < gb; ++g2)
            vb += pbb[(size_t)(g2 * PSTRIDE + KWS) * NE + u];
        snL[0][u] = va;
        snL[1][u] = vb;
    }
    for (int u = lane; u < WIN * ZD; u += 64) {
        zbS[0][u] = sra[u];
        zbS[1][u] = srb[u];
    }
    // no __syncthreads: same-wave LDS producer/consumer, DS pipe is in-order

    const int j     = lane;
    const int off_j = j * (ZD - 1) - (j * (j - 1)) / 2;   // eidx(j, R) = off_j + R
    const int zoff  = (j - DD) * ZD;

    PackP<21> Aa, Ab;
    init_rec<0>(Aa, j, off_j, zoff, snL[0], zbS[0]);  // lanes >= 42 get zeros
    init_rec<0>(Ab, j, off_j, zoff, snL[1], zbS[1]);

    elim_all2(Aa, Ab, std::make_integer_sequence<int, DD>{});

    if (lane >= DD && lane < DD + 10) {
        kdump<0>(Aa, KlS[0], lane - DD);
        kdump<0>(Ab, KlS[1], lane - DD);
    }
    // no __syncthreads: kdump (DS writes) -> tinit (DS reads) same wave, in-order

    const int sys = lane >> 3;           // sub-system index: n = 8w + sys
    const int row = lane & 7;
    const int pbB = (lane & ~7) << 2;    // byte base of own 8-lane group (in-wave)

    Pack<12> Ta, Tb;
    tinit<0>(Ta, row, sys, KlS[0], zbS[0]);
    tinit<0>(Tb, row, sys, KlS[1], zbS[1]);
    float diag_a = 1.0f, diag_b = 1.0f;
    gjp_all2(Ta, Tb, pbB, row, diag_a, diag_b, std::make_integer_sequence<int, 8>{});

    // per-row contributions; inactive rows (row > sys) have zero RHS -> 0
    float dia = (diag_a > 1e-30f || diag_a < -1e-30f) ? 1.0f / diag_a : 0.0f;
    float dib = (diag_b > 1e-30f || diag_b < -1e-30f) ? 1.0f / diag_b : 0.0f;
    double s1a = (double)(pget<8>(Ta) * dia),  s1b = (double)(pget<8>(Tb) * dib);
    double s2a = (double)(pget<9>(Ta) * dia),  s2b = (double)(pget<9>(Tb) * dib);
    double r1a = (double)(pget<10>(Ta) * dia), r1b = (double)(pget<10>(Tb) * dib);
    double r2a = (double)(pget<11>(Ta) * dia), r2b = (double)(pget<11>(Tb) * dib);
    double gga = (double)KlS[0][80 + row] - (double)zbS[0][row * ZD + DD];
    double ggb = (double)KlS[1][80 + row] - (double)zbS[1][row * ZD + DD];
    double cda = gga * (s1a - s2a), cdb = ggb * (s1b - s2b);
    double cna = gga * (r1a - r2a), cnb = ggb * (r1b - r2b);
#pragma unroll
    for (int m = 1; m < 8; m <<= 1) {
        cda += __shfl_xor(cda, m, 8);
        cna += __shfl_xor(cna, m, 8);
        cdb += __shfl_xor(cdb, m, 8);
        cnb += __shfl_xor(cnb, m, 8);
    }

    double dena = (double)snL[0][592] - (double)KlS[0][88] + cda;
    double numa = (double)snL[0][593] - (double)KlS[0][89] + cna;
    double denb = (double)snL[1][592] - (double)KlS[1][88] + cdb;
    double numb = (double)snL[1][593] - (double)KlS[1][89] + cnb;
    double vala = (dena > 0.0) ? numa / dena : 0.0;
    double valb = (denb > 0.0) ? numb / denb : 0.0;
    if (!isfinite(vala)) vala = 0.0;
    if (!isfinite(valb)) valb = 0.0;
    if (row == 0) {
        out[ba * NN + wa * WIN + sys] = (float)vala;
        out[bb * NN + wb * WIN + sys] = (float)valb;
    }
}

extern "C" void kernel_launch(void* const* d_in, const int* in_sizes, int n_in,
                              void* d_out, int out_size, void* d_ws, size_t ws_size,
                              hipStream_t stream) {
    const float* xtys = (const float*)d_in[0];
    float* out = (float*)d_out;
    float* P = (float*)d_ws;   // [BB][SEG][17][NE] fp32 = 10.36 MB

    hipLaunchKernelGGL(dml_gram, dim3(BB * SEG * CH), dim3(256), 0, stream, xtys, P, out);
    hipLaunchKernelGGL(dml_solve, dim3(BB * WACT / 2), dim3(64), 0, stream, xtys, P, out);
}

// Round 10
// 90.932 us; speedup vs baseline: 1.1676x; 1.1676x over previous
//
#include <hip/hip_runtime.h>
#include <math.h>
#include <utility>

#define BB 64
#define NN 512
#define DD 32
#define ZD 34            // DD + 2 (x..., t, y)
#define NE 595           // ZD*(ZD+1)/2 upper-triangular entries
#define WIN 8
#define NW 64            // NN / WIN windows
#define WACT 60          // active windows w = 4..63 (n <= 31 is rank-deficient -> 0)

// fused gram+scan geometry (entry-per-thread, 128-row segments)
#define SEG 4            // s-segments per batch (128 rows each)
#define RS 128           // rows per segment
#define KWS 16           // windows per segment
#define CH 4             // e-chunks per (b,seg)
#define ECH 149          // entries per chunk (4*149 >= 595)
#define PSTRIDE 17       // 16 exclusive in-segment snapshots + segment total

#define SPW 5            // solve: systems (waves) per WG; 3840/5 = 768 WGs = 3/CU exact

using f2 = __attribute__((ext_vector_type(2))) float;

// entry e -> (i,j), i <= j, row-major upper triangle of ZD x ZD
__device__ inline void ent2ij(int e, int& i, int& j) {
    int ii = 0, rem = e;
    while (rem >= ZD - ii) { rem -= (ZD - ii); ++ii; }
    i = ii; j = ii + rem;
}

// ---- recursive struct-of-scalars: SROA-guaranteed register residency ----
template<int N> struct Pack { Pack<N - 1> head; float v; };
template<> struct Pack<1> { float v; };
template<int I, int N> __device__ __forceinline__ float& pget(Pack<N>& p) {
    static_assert(I < N, "oob");
    if constexpr (I == N - 1) return p.v;
    else return pget<I, N - 1>(p.head);
}

// float2-pair variant (pair p = rows 2p, 2p+1)
template<int N> struct PackP { PackP<N - 1> head; f2 v; };
template<> struct PackP<1> { f2 v; };
template<int I, int N> __device__ __forceinline__ f2& ppget(PackP<N>& p) {
    static_assert(I < N, "oob");
    if constexpr (I == N - 1) return p.v;
    else return ppget<I, N - 1>(p.head);
}
template<int R> __device__ __forceinline__ float prow(PackP<21>& p) {
    static_assert(R < 42, "oob");
    if constexpr (R & 1) return ppget<R / 2>(p).y;
    else                 return ppget<R / 2>(p).x;
}

__device__ __forceinline__ float rdlane(float x, int srclane) {
    return __int_as_float(__builtin_amdgcn_readlane(__float_as_int(x), srclane));
}
__device__ __forceinline__ float bperm(int byteaddr, float x) {
    return __int_as_float(__builtin_amdgcn_ds_bpermute(byteaddr, __float_as_int(x)));
}
// single-instruction v_rcp_f32 (~1 ulp): removes the ~9-instr precise-div
// sequence from the HEAD of every elimination/GJ step's dependency chain.
__device__ __forceinline__ float frcp(float x) {
    return __builtin_amdgcn_rcpf(x);
}

// Fused window-partial + prefix-scan. Block = (b, s-segment, e-chunk).
// Each thread owns ONE triangle entry e. ILP form: 16 INDEPENDENT 8-fma fp64
// window partials + 16 serial adds. Emits 16 exclusive window snapshots +
// segment total to P[b][seg][17][NE]. Folds output init: logs[.]=0, means=0
// for n < 32.
__global__ __launch_bounds__(256) void dml_gram(const float* __restrict__ xtys,
                                                float* __restrict__ P,
                                                float* __restrict__ out) {
    const int t   = threadIdx.x;
    const int blk = blockIdx.x;                  // ((b*SEG + g)*CH + c)
    const int c   = blk % CH;
    const int bg  = blk / CH;
    const int g   = bg % SEG;
    const int b   = bg / SEG;

    const int gid = blk * 256 + t;
    if (gid < BB * NN) out[BB * NN + gid] = 0.0f;
    if (gid < BB * DD) out[(gid >> 5) * NN + (gid & 31)] = 0.0f;

    __shared__ float zs[RS * ZD];                // 17408 B
    const float* src = xtys + ((size_t)b * NN + (size_t)g * RS) * ZD;
    for (int u = t; u < RS * ZD; u += 256) zs[u] = src[u];
    __syncthreads();

    const int e = c * ECH + t;
    if (t < ECH && e < NE) {
        int i, j;
        ent2ij(e, i, j);
        float* pdst = P + (size_t)(b * SEG + g) * PSTRIDE * NE + e;
        double acc = 0.0;
#pragma unroll
        for (int k = 0; k < KWS; ++k) {
            pdst[k * NE] = (float)acc;           // exclusive: before window k's rows
            double wsum = 0.0;                   // independent chain per window
#pragma unroll
            for (int s8 = 0; s8 < WIN; ++s8) {
                const float* row = &zs[(k * WIN + s8) * ZD];
                wsum = fma((double)row[i], (double)row[j], wsum);
            }
            acc += wsum;
        }
        pdst[KWS * NE] = (float)acc;             // segment total
    }
}

// ---- solve: lane = COLUMN j of the symmetric bordered 42x42 matrix
// [[G0, W],[W^T, 0]], W = [x_1..x_8, Xtt0, Xty0]; A[r] = M[r][j], stored as
// 21 float2 pairs. Elimination step K: cross-lane values are wave-uniform
// (from lane K) -> v_readlane; each pair updated with one vector op. Pair
// (K>>1) at even K also touches dead pivot row K — safe: pivot rows are only
// read (piv, t) BEFORE the updates of their own step, never afterwards.

template<int R> __device__ __forceinline__
float initval(int j, int off_j, int zoff, const float* snL, const float* zb) {
    constexpr int RC = (R < DD) ? (R * ZD - (R * (R - 1)) / 2 - R) : 0;
    if constexpr (R < DD) {
        float v = 0.0f;
        if (j < DD) {
            int idx = (R < j) ? (RC + j) : (off_j + R);
            v = snL[idx];
        } else if (j < DD + WIN) {
            v = zb[zoff + R];
        } else if (j == 40) {
            v = snL[RC + DD];                    // Xtt0[R]
        } else if (j == 41) {
            v = snL[RC + DD + 1];                // Xty0[R]
        }
        return v;
    } else if constexpr (R < DD + WIN) {
        return (j < DD) ? zb[(R - DD) * ZD + j] : 0.0f;
    } else if constexpr (R == 40) {
        return (j < DD) ? snL[off_j + DD] : 0.0f;
    } else {
        return (j < DD) ? snL[off_j + DD + 1] : 0.0f;
    }
}
template<int P> __device__ __forceinline__
void init_rec(PackP<21>& A, int j, int off_j, int zoff,
              const float* snL, const float* zb) {
    if constexpr (P < 21) {
        f2 q;
        q.x = initval<2 * P>(j, off_j, zoff, snL, zb);
        q.y = initval<2 * P + 1>(j, off_j, zoff, snL, zb);
        ppget<P>(A) = q;
        init_rec<P + 1>(A, j, off_j, zoff, snL, zb);
    }
}

template<int K, int P> __device__ __forceinline__
void elim_pairs(PackP<21>& A, f2 t2) {
    if constexpr (P < 21) {
        f2 fr2;
        fr2.x = rdlane(prow<2 * P>(A), K);       // M[2P][K], wave-uniform
        fr2.y = rdlane(prow<2 * P + 1>(A), K);
        ppget<P>(A) -= fr2 * t2;
        elim_pairs<K, P + 1>(A, t2);
    }
}
template<int K> __device__ __forceinline__
void elim_step(PackP<21>& A) {
    float piv  = rdlane(prow<K>(A), K);          // M[K][K]
    float invp = (piv > 1e-30f) ? frcp(piv) : 0.0f;
    float t    = invp * prow<K>(A);              // invp*M[K][j]; 0 for done cols
    f2 t2; t2.x = t; t2.y = t;
    elim_pairs<K, (K + 1) / 2>(A, t2);
}
template<int... Ks> __device__ __forceinline__
void elim_all(PackP<21>& A, std::integer_sequence<int, Ks...>) {
    ((elim_step<Ks>(A)), ...);
}

template<int R> __device__ __forceinline__
void kdump(PackP<21>& A, float* Kl, int c) {     // lanes 32..41: column c of K
    if constexpr (R < DD + 10) {
        if constexpr (R >= DD)
            Kl[(R - DD) * 10 + c] = -prow<R>(A);
        kdump<R + 1>(A, Kl, c);
    }
}

// ---- row-parallel 8x8 GJ: lane = (sys, row) = (lane>>3, lane&7). Each lane
// holds ONE row (12 floats) in registers; pivot-row broadcast via ds_bpermute
// within the 8-lane group. Inactive rows (row > sys) are identity rows with
// zero RHS -> f = 0 forever, contribute exactly 0.
template<int L> __device__ __forceinline__
void tinit(Pack<12>& T, int row, int sys, const float* Kl, const float* zb) {
    if constexpr (L < 12) {
        float v;
        if constexpr (L < 8) {
            float kij = (row <= sys && L <= sys) ? Kl[row * 10 + L] : 0.0f;
            v = kij + ((row == L) ? 1.0f : 0.0f);
        } else if constexpr (L == 8)  v = (row <= sys) ? Kl[row * 10 + 8] : 0.0f;       // KUp
        else if constexpr (L == 9)    v = (row <= sys) ? zb[row * ZD + DD] : 0.0f;      // t_i
        else if constexpr (L == 10)   v = (row <= sys) ? Kl[row * 10 + 9] : 0.0f;       // KUq
        else                          v = (row <= sys) ? zb[row * ZD + DD + 1] : 0.0f;  // y_i
        pget<L>(T) = v;
        tinit<L + 1>(T, row, sys, Kl, zb);
    }
}
template<int K, int J> __device__ __forceinline__
void gjp_cols(Pack<12>& T, float f, int pb) {
    if constexpr (J < 12) {
        float pk = bperm(pb + 4 * K, pget<J>(T));   // pivot row K, col J
        pget<J>(T) = fmaf(-f, pk, pget<J>(T));
        gjp_cols<K, J + 1>(T, f, pb);
    }
}
template<int K> __device__ __forceinline__
void gjp_step(Pack<12>& T, int pb, int row, float& diag) {
    float pkK  = bperm(pb + 4 * K, pget<K>(T));     // M[K][K] of own system
    float invp = (pkK > 1e-30f || pkK < -1e-30f) ? frcp(pkK) : 0.0f;
    float f    = (row == K) ? 0.0f : pget<K>(T) * invp;
    gjp_cols<K, K + 1>(T, f, pb);
    if (row == K) diag = pget<K>(T);                // T[K][K] final after step K
}
template<int... Ks> __device__ __forceinline__
void gjp_all(Pack<12>& T, int pb, int row, float& diag,
             std::integer_sequence<int, Ks...>) {
    ((gjp_step<Ks>(T, pb, row, diag)), ...);
}

// FIVE systems per 320-thread workgroup: wave wid owns system
// id = blockIdx.x*5 + wid = (b, w>=4), private per-wave LDS slices, no
// __syncthreads (DS pipe in-order per wave; slices not shared). 3840/5 = 768
// WGs = EXACTLY 3 per CU: no WG-count imbalance tail.
// Snapshot Sn[w] = piece[g][k] + sum_{g'<g} total[g'], g=w>>4, k=w&15.
// Readlane packed-pair elimination (v_rcp pivots) -> K = W^T G0^-1 W (10x10),
// then row-parallel GJ across all 64 lanes (8 sub-systems x 8 rows).
//   den = Stt0 - Kpp + sum_i (KpU_i - t_i)(s1_i - s2_i), s1=S^-1 KUp, s2=S^-1 t
//   num = Sty0 - Kpq + sum_i (KpU_i - t_i)(r1_i - r2_i), r1=S^-1 KUq, r2=S^-1 y
__global__ __launch_bounds__(320) void dml_solve(const float* __restrict__ xtys,
                                                 const float* __restrict__ P,
                                                 float* __restrict__ out) {
    const int wid  = threadIdx.x >> 6;         // 0..4
    const int lane = threadIdx.x & 63;
    const int id   = blockIdx.x * SPW + wid;   // 0 .. BB*WACT-1 exactly
    const int w    = (id % WACT) + 4;
    const int b    = id / WACT;
    const int g    = w >> 4;
    const int k    = w & 15;

    __shared__ float snL[SPW][NE];
    __shared__ float zb[SPW][WIN * ZD];
    __shared__ float Kl[SPW][100];       // K = W^T G0^-1 W (10x10)
    float* snW = snL[wid];
    float* zbW = zb[wid];
    float* KlW = Kl[wid];

    const float* pb_  = P + (size_t)b * SEG * PSTRIDE * NE;
    const float* src  = xtys + ((size_t)b * NN + (size_t)w * WIN) * ZD;
    for (int u = lane; u < NE; u += 64) {
        float v = pb_[(size_t)(g * PSTRIDE + k) * NE + u];
        for (int g2 = 0; g2 < g; ++g2)
            v += pb_[(size_t)(g2 * PSTRIDE + KWS) * NE + u];
        snW[u] = v;
    }
    for (int u = lane; u < WIN * ZD; u += 64) zbW[u] = src[u];
    // no __syncthreads: same-wave LDS producer/consumer, DS pipe is in-order

    const int j     = lane;
    const int off_j = j * (ZD - 1) - (j * (j - 1)) / 2;   // eidx(j, R) = off_j + R
    const int zoff  = (j - DD) * ZD;

    PackP<21> A;
    init_rec<0>(A, j, off_j, zoff, snW, zbW);  // lanes >= 42 get zeros

    elim_all(A, std::make_integer_sequence<int, DD>{});

    if (lane >= DD && lane < DD + 10) kdump<0>(A, KlW, lane - DD);
    // no __syncthreads: kdump (DS writes) -> tinit (DS reads) same wave, in-order

    const int sys = lane >> 3;           // sub-system index: n = 8w + sys
    const int row = lane & 7;
    const int pbB = (lane & ~7) << 2;    // byte base of own 8-lane group (in-wave)

    Pack<12> T;
    tinit<0>(T, row, sys, KlW, zbW);
    float diag = 1.0f;
    gjp_all(T, pbB, row, diag, std::make_integer_sequence<int, 8>{});

    // per-row contribution; inactive rows (row > sys) have zero RHS -> 0
    float dinv = (diag > 1e-30f || diag < -1e-30f) ? frcp(diag) : 0.0f;
    double s1 = (double)(pget<8>(T) * dinv);
    double s2 = (double)(pget<9>(T) * dinv);
    double r1 = (double)(pget<10>(T) * dinv);
    double r2 = (double)(pget<11>(T) * dinv);
    double gg = (double)KlW[80 + row] - (double)zbW[row * ZD + DD]; // KpU_i - t_i
    double cd = gg * (s1 - s2);
    double cn = gg * (r1 - r2);
#pragma unroll
    for (int m = 1; m < 8; m <<= 1) {
        cd += __shfl_xor(cd, m, 8);
        cn += __shfl_xor(cn, m, 8);
    }

    double Stt0 = (double)snW[592];
    double Sty0 = (double)snW[593];
    double den  = Stt0 - (double)KlW[88] + cd;  // Stt0 - Kpp + dterm
    double num  = Sty0 - (double)KlW[89] + cn;  // Sty0 - Kpq + nterm
    double val  = (den > 0.0) ? num / den : 0.0;
    if (!isfinite(val)) val = 0.0;
    if (row == 0) out[b * NN + w * WIN + sys] = (float)val;
}

extern "C" void kernel_launch(void* const* d_in, const int* in_sizes, int n_in,
                              void* d_out, int out_size, void* d_ws, size_t ws_size,
                              hipStream_t stream) {
    const float* xtys = (const float*)d_in[0];
    float* out = (float*)d_out;
    float* P = (float*)d_ws;   // [BB][SEG][17][NE] fp32 = 10.36 MB

    hipLaunchKernelGGL(dml_gram, dim3(BB * SEG * CH), dim3(256), 0, stream, xtys, P, out);
    hipLaunchKernelGGL(dml_solve, dim3(BB * WACT / SPW), dim3(320), 0, stream, xtys, P, out);
}

// Round 11
// 90.527 us; speedup vs baseline: 1.1728x; 1.0045x over previous
//
#include <hip/hip_runtime.h>
#include <math.h>
#include <utility>

#define BB 64
#define NN 512
#define DD 32
#define ZD 34            // DD + 2 (x..., t, y)
#define NE 595           // ZD*(ZD+1)/2 upper-triangular entries
#define WIN 8
#define NW 64            // NN / WIN windows
#define WACT 60          // active windows w = 4..63 (n <= 31 is rank-deficient -> 0)

// fused gram+scan geometry (entry-per-thread, 128-row segments)
#define SEG 4            // s-segments per batch (128 rows each)
#define RS 128           // rows per segment
#define KWS 16           // windows per segment
#define CH 4             // e-chunks per (b,seg)
#define ECH 149          // entries per chunk (4*149 >= 595)
#define PSTRIDE 17       // 16 exclusive in-segment snapshots + segment total

#define SPW 5            // solve: systems (waves) per WG; 3840/5 = 768 WGs = 3/CU exact

using f2 = __attribute__((ext_vector_type(2))) float;

// entry e -> (i,j), i <= j, row-major upper triangle of ZD x ZD
__device__ inline void ent2ij(int e, int& i, int& j) {
    int ii = 0, rem = e;
    while (rem >= ZD - ii) { rem -= (ZD - ii); ++ii; }
    i = ii; j = ii + rem;
}

// ---- recursive struct-of-scalars: SROA-guaranteed register residency ----
template<int N> struct Pack { Pack<N - 1> head; float v; };
template<> struct Pack<1> { float v; };
template<int I, int N> __device__ __forceinline__ float& pget(Pack<N>& p) {
    static_assert(I < N, "oob");
    if constexpr (I == N - 1) return p.v;
    else return pget<I, N - 1>(p.head);
}

// float2-pair variant (pair p = rows 2p, 2p+1)
template<int N> struct PackP { PackP<N - 1> head; f2 v; };
template<> struct PackP<1> { f2 v; };
template<int I, int N> __device__ __forceinline__ f2& ppget(PackP<N>& p) {
    static_assert(I < N, "oob");
    if constexpr (I == N - 1) return p.v;
    else return ppget<I, N - 1>(p.head);
}
template<int R> __device__ __forceinline__ float prow(PackP<21>& p) {
    static_assert(R < 42, "oob");
    if constexpr (R & 1) return ppget<R / 2>(p).y;
    else                 return ppget<R / 2>(p).x;
}

__device__ __forceinline__ float rdlane(float x, int srclane) {
    return __int_as_float(__builtin_amdgcn_readlane(__float_as_int(x), srclane));
}
__device__ __forceinline__ float bperm(int byteaddr, float x) {
    return __int_as_float(__builtin_amdgcn_ds_bpermute(byteaddr, __float_as_int(x)));
}
// single-instruction v_rcp_f32 (~1 ulp): removes the ~9-instr precise-div
// sequence from the HEAD of every elimination/GJ step's dependency chain.
__device__ __forceinline__ float frcp(float x) {
    return __builtin_amdgcn_rcpf(x);
}

// Fused window-partial + prefix-scan. Block = (b, s-segment, e-chunk).
// Each thread owns ONE triangle entry e. ILP form: 16 INDEPENDENT 8-fma fp64
// window partials + 16 serial adds. Emits 16 exclusive window snapshots +
// segment total to P[b][seg][17][NE]. Folds output init: logs[.]=0, means=0
// for n < 32.
__global__ __launch_bounds__(256) void dml_gram(const float* __restrict__ xtys,
                                                float* __restrict__ P,
                                                float* __restrict__ out) {
    const int t   = threadIdx.x;
    const int blk = blockIdx.x;                  // ((b*SEG + g)*CH + c)
    const int c   = blk % CH;
    const int bg  = blk / CH;
    const int g   = bg % SEG;
    const int b   = bg / SEG;

    const int gid = blk * 256 + t;
    if (gid < BB * NN) out[BB * NN + gid] = 0.0f;
    if (gid < BB * DD) out[(gid >> 5) * NN + (gid & 31)] = 0.0f;

    __shared__ float zs[RS * ZD];                // 17408 B
    const float* src = xtys + ((size_t)b * NN + (size_t)g * RS) * ZD;
    for (int u = t; u < RS * ZD; u += 256) zs[u] = src[u];
    __syncthreads();

    const int e = c * ECH + t;
    if (t < ECH && e < NE) {
        int i, j;
        ent2ij(e, i, j);
        float* pdst = P + (size_t)(b * SEG + g) * PSTRIDE * NE + e;
        double acc = 0.0;
#pragma unroll
        for (int k = 0; k < KWS; ++k) {
            pdst[k * NE] = (float)acc;           // exclusive: before window k's rows
            double wsum = 0.0;                   // independent chain per window
#pragma unroll
            for (int s8 = 0; s8 < WIN; ++s8) {
                const float* row = &zs[(k * WIN + s8) * ZD];
                wsum = fma((double)row[i], (double)row[j], wsum);
            }
            acc += wsum;
        }
        pdst[KWS * NE] = (float)acc;             // segment total
    }
}

// ---- solve: lane = COLUMN j of the symmetric bordered 42x42 matrix
// [[G0, W],[W^T, 0]], W = [x_1..x_8, Xtt0, Xty0]; A[r] = M[r][j], stored as
// 21 float2 pairs. Elimination step K: cross-lane values are wave-uniform
// (from lane K) -> v_readlane; each pair updated with one vector op. Pair
// (K>>1) at even K also touches dead pivot row K — safe: pivot rows are only
// read (piv, t) BEFORE the updates of their own step, never afterwards.

template<int R> __device__ __forceinline__
float initval(int j, int off_j, int zoff, const float* snL, const float* zb) {
    constexpr int RC = (R < DD) ? (R * ZD - (R * (R - 1)) / 2 - R) : 0;
    if constexpr (R < DD) {
        float v = 0.0f;
        if (j < DD) {
            int idx = (R < j) ? (RC + j) : (off_j + R);
            v = snL[idx];
        } else if (j < DD + WIN) {
            v = zb[zoff + R];
        } else if (j == 40) {
            v = snL[RC + DD];                    // Xtt0[R]
        } else if (j == 41) {
            v = snL[RC + DD + 1];                // Xty0[R]
        }
        return v;
    } else if constexpr (R < DD + WIN) {
        return (j < DD) ? zb[(R - DD) * ZD + j] : 0.0f;
    } else if constexpr (R == 40) {
        return (j < DD) ? snL[off_j + DD] : 0.0f;
    } else {
        return (j < DD) ? snL[off_j + DD + 1] : 0.0f;
    }
}
template<int P> __device__ __forceinline__
void init_rec(PackP<21>& A, int j, int off_j, int zoff,
              const float* snL, const float* zb) {
    if constexpr (P < 21) {
        f2 q;
        q.x = initval<2 * P>(j, off_j, zoff, snL, zb);
        q.y = initval<2 * P + 1>(j, off_j, zoff, snL, zb);
        ppget<P>(A) = q;
        init_rec<P + 1>(A, j, off_j, zoff, snL, zb);
    }
}

template<int K, int P> __device__ __forceinline__
void elim_pairs(PackP<21>& A, f2 t2) {
    if constexpr (P < 21) {
        f2 fr2;
        fr2.x = rdlane(prow<2 * P>(A), K);       // M[2P][K], wave-uniform
        fr2.y = rdlane(prow<2 * P + 1>(A), K);
        ppget<P>(A) -= fr2 * t2;
        elim_pairs<K, P + 1>(A, t2);
    }
}
template<int K> __device__ __forceinline__
void elim_step(PackP<21>& A) {
    float piv  = rdlane(prow<K>(A), K);          // M[K][K]
    float invp = (piv > 1e-30f) ? frcp(piv) : 0.0f;
    float t    = invp * prow<K>(A);              // invp*M[K][j]; 0 for done cols
    f2 t2; t2.x = t; t2.y = t;
    elim_pairs<K, (K + 1) / 2>(A, t2);
}
template<int... Ks> __device__ __forceinline__
void elim_all(PackP<21>& A, std::integer_sequence<int, Ks...>) {
    ((elim_step<Ks>(A)), ...);
}

template<int R> __device__ __forceinline__
void kdump(PackP<21>& A, float* Kl, int c) {     // lanes 32..41: column c of K
    if constexpr (R < DD + 10) {
        if constexpr (R >= DD)
            Kl[(R - DD) * 10 + c] = -prow<R>(A);
        kdump<R + 1>(A, Kl, c);
    }
}

// ---- row-parallel 8x8 GJ: lane = (sys, row) = (lane>>3, lane&7). Each lane
// holds ONE row (12 floats) in registers; pivot-row broadcast via ds_bpermute
// within the 8-lane group. Inactive rows (row > sys) are identity rows with
// zero RHS -> f = 0 forever, contribute exactly 0.
template<int L> __device__ __forceinline__
void tinit(Pack<12>& T, int row, int sys, const float* Kl, const float* zb) {
    if constexpr (L < 12) {
        float v;
        if constexpr (L < 8) {
            float kij = (row <= sys && L <= sys) ? Kl[row * 10 + L] : 0.0f;
            v = kij + ((row == L) ? 1.0f : 0.0f);
        } else if constexpr (L == 8)  v = (row <= sys) ? Kl[row * 10 + 8] : 0.0f;       // KUp
        else if constexpr (L == 9)    v = (row <= sys) ? zb[row * ZD + DD] : 0.0f;      // t_i
        else if constexpr (L == 10)   v = (row <= sys) ? Kl[row * 10 + 9] : 0.0f;       // KUq
        else                          v = (row <= sys) ? zb[row * ZD + DD + 1] : 0.0f;  // y_i
        pget<L>(T) = v;
        tinit<L + 1>(T, row, sys, Kl, zb);
    }
}
template<int K, int J> __device__ __forceinline__
void gjp_cols(Pack<12>& T, float f, int pb) {
    if constexpr (J < 12) {
        float pk = bperm(pb + 4 * K, pget<J>(T));   // pivot row K, col J
        pget<J>(T) = fmaf(-f, pk, pget<J>(T));
        gjp_cols<K, J + 1>(T, f, pb);
    }
}
template<int K> __device__ __forceinline__
void gjp_step(Pack<12>& T, int pb, int row, float& diag) {
    float pkK  = bperm(pb + 4 * K, pget<K>(T));     // M[K][K] of own system
    float invp = (pkK > 1e-30f || pkK < -1e-30f) ? frcp(pkK) : 0.0f;
    float f    = (row == K) ? 0.0f : pget<K>(T) * invp;
    gjp_cols<K, K + 1>(T, f, pb);
    if (row == K) diag = pget<K>(T);                // T[K][K] final after step K
}
template<int... Ks> __device__ __forceinline__
void gjp_all(Pack<12>& T, int pb, int row, float& diag,
             std::integer_sequence<int, Ks...>) {
    ((gjp_step<Ks>(T, pb, row, diag)), ...);
}

// FIVE systems per 320-thread workgroup: wave wid owns system
// id = blockIdx.x*5 + wid = (b, w>=4), private per-wave LDS slices, no
// __syncthreads (DS pipe in-order per wave; slices not shared). 3840/5 = 768
// WGs = EXACTLY 3 per CU: no WG-count imbalance tail.
// __launch_bounds__(320, 1): min-1-wave-per-EU is the WEAKEST occupancy
// constraint — pins the allocator to full architectural-VGPR residency for
// the 42-float column state (round-10 counters showed VGPR_Count=28 ->
// AGPR-split with v_accvgpr shuffling on every elimination access).
// Snapshot Sn[w] = piece[g][k] + sum_{g'<g} total[g'], g=w>>4, k=w&15.
// Readlane packed-pair elimination (v_rcp pivots) -> K = W^T G0^-1 W (10x10),
// then row-parallel GJ across all 64 lanes (8 sub-systems x 8 rows).
//   den = Stt0 - Kpp + sum_i (KpU_i - t_i)(s1_i - s2_i), s1=S^-1 KUp, s2=S^-1 t
//   num = Sty0 - Kpq + sum_i (KpU_i - t_i)(r1_i - r2_i), r1=S^-1 KUq, r2=S^-1 y
__global__ __launch_bounds__(320, 1) void dml_solve(const float* __restrict__ xtys,
                                                    const float* __restrict__ P,
                                                    float* __restrict__ out) {
    const int wid  = threadIdx.x >> 6;         // 0..4
    const int lane = threadIdx.x & 63;
    const int id   = blockIdx.x * SPW + wid;   // 0 .. BB*WACT-1 exactly
    const int w    = (id % WACT) + 4;
    const int b    = id / WACT;
    const int g    = w >> 4;
    const int k    = w & 15;

    __shared__ float snL[SPW][NE];
    __shared__ float zb[SPW][WIN * ZD];
    __shared__ float Kl[SPW][100];       // K = W^T G0^-1 W (10x10)
    float* snW = snL[wid];
    float* zbW = zb[wid];
    float* KlW = Kl[wid];

    const float* pb_  = P + (size_t)b * SEG * PSTRIDE * NE;
    const float* src  = xtys + ((size_t)b * NN + (size_t)w * WIN) * ZD;
    for (int u = lane; u < NE; u += 64) {
        float v = pb_[(size_t)(g * PSTRIDE + k) * NE + u];
        for (int g2 = 0; g2 < g; ++g2)
            v += pb_[(size_t)(g2 * PSTRIDE + KWS) * NE + u];
        snW[u] = v;
    }
    for (int u = lane; u < WIN * ZD; u += 64) zbW[u] = src[u];
    // no __syncthreads: same-wave LDS producer/consumer, DS pipe is in-order

    const int j     = lane;
    const int off_j = j * (ZD - 1) - (j * (j - 1)) / 2;   // eidx(j, R) = off_j + R
    const int zoff  = (j - DD) * ZD;

    PackP<21> A;
    init_rec<0>(A, j, off_j, zoff, snW, zbW);  // lanes >= 42 get zeros

    elim_all(A, std::make_integer_sequence<int, DD>{});

    if (lane >= DD && lane < DD + 10) kdump<0>(A, KlW, lane - DD);
    // no __syncthreads: kdump (DS writes) -> tinit (DS reads) same wave, in-order

    const int sys = lane >> 3;           // sub-system index: n = 8w + sys
    const int row = lane & 7;
    const int pbB = (lane & ~7) << 2;    // byte base of own 8-lane group (in-wave)

    Pack<12> T;
    tinit<0>(T, row, sys, KlW, zbW);
    float diag = 1.0f;
    gjp_all(T, pbB, row, diag, std::make_integer_sequence<int, 8>{});

    // per-row contribution; inactive rows (row > sys) have zero RHS -> 0
    float dinv = (diag > 1e-30f || diag < -1e-30f) ? frcp(diag) : 0.0f;
    double s1 = (double)(pget<8>(T) * dinv);
    double s2 = (double)(pget<9>(T) * dinv);
    double r1 = (double)(pget<10>(T) * dinv);
    double r2 = (double)(pget<11>(T) * dinv);
    double gg = (double)KlW[80 + row] - (double)zbW[row * ZD + DD]; // KpU_i - t_i
    double cd = gg * (s1 - s2);
    double cn = gg * (r1 - r2);
#pragma unroll
    for (int m = 1; m < 8; m <<= 1) {
        cd += __shfl_xor(cd, m, 8);
        cn += __shfl_xor(cn, m, 8);
    }

    double Stt0 = (double)snW[592];
    double Sty0 = (double)snW[593];
    double den  = Stt0 - (double)KlW[88] + cd;  // Stt0 - Kpp + dterm
    double num  = Sty0 - (double)KlW[89] + cn;  // Sty0 - Kpq + nterm
    double val  = (den > 0.0) ? num / den : 0.0;
    if (!isfinite(val)) val = 0.0;
    if (row == 0) out[b * NN + w * WIN + sys] = (float)val;
}

extern "C" void kernel_launch(void* const* d_in, const int* in_sizes, int n_in,
                              void* d_out, int out_size, void* d_ws, size_t ws_size,
                              hipStream_t stream) {
    const float* xtys = (const float*)d_in[0];
    float* out = (float*)d_out;
    float* P = (float*)d_ws;   // [BB][SEG][17][NE] fp32 = 10.36 MB

    hipLaunchKernelGGL(dml_gram, dim3(BB * SEG * CH), dim3(256), 0, stream, xtys, P, out);
    hipLaunchKernelGGL(dml_solve, dim3(BB * WACT / SPW), dim3(320), 0, stream, xtys, P, out);
}